// Round 6
// baseline (1239.231 us; speedup 1.0000x reference)
//
#include <hip/hip_runtime.h>
#include <hip/hip_bf16.h>
#include <math.h>

#define B_   8
#define C_   64
#define N_   65536
#define R_   32
#define R3_  32768
#define RP_  34
#define RP2_ 1156      // 34*34
#define RP3_ 39304     // 34^3

typedef short short8v __attribute__((ext_vector_type(8)));
typedef float floatx4 __attribute__((ext_vector_type(4)));

__device__ inline float bf2f(short u) {
    return __uint_as_float(((unsigned)(unsigned short)u) << 16);
}
__device__ inline unsigned short f2bf(float f) {
    __hip_bfloat16 h = __float2bfloat16(f);
    return *reinterpret_cast<unsigned short*>(&h);
}
__device__ inline void atomicMaxF(float* addr, float v) {
    atomicMax((unsigned int*)addr, __float_as_uint(v));
}

// ---------------- stats ----------------
__global__ __launch_bounds__(256) void k_stats_sum(const float* __restrict__ coords,
                                                   float* __restrict__ stats) {
    int b = blockIdx.y;
    int tid = threadIdx.x;
    const float* cb = coords + (size_t)b * 3 * N_;
    float sx = 0.f, sy = 0.f, sz = 0.f;
    int base = blockIdx.x * 2048;
    for (int k = 0; k < 8; ++k) {
        int n = base + k * 256 + tid;
        sx += cb[n];
        sy += cb[N_ + n];
        sz += cb[2 * N_ + n];
    }
    for (int o = 32; o > 0; o >>= 1) {
        sx += __shfl_down(sx, o);
        sy += __shfl_down(sy, o);
        sz += __shfl_down(sz, o);
    }
    if ((tid & 63) == 0) {
        atomicAdd(&stats[b * 8 + 0], sx);
        atomicAdd(&stats[b * 8 + 1], sy);
        atomicAdd(&stats[b * 8 + 2], sz);
    }
}

__global__ __launch_bounds__(256) void k_stats_max(const float* __restrict__ coords,
                                                   float* __restrict__ stats) {
    int b = blockIdx.y;
    int tid = threadIdx.x;
    const float* cb = coords + (size_t)b * 3 * N_;
    float mx = stats[b * 8 + 0] * (1.f / N_);
    float my = stats[b * 8 + 1] * (1.f / N_);
    float mz = stats[b * 8 + 2] * (1.f / N_);
    float vm = 0.f;
    int base = blockIdx.x * 2048;
    for (int k = 0; k < 8; ++k) {
        int n = base + k * 256 + tid;
        float dx = cb[n] - mx, dy = cb[N_ + n] - my, dz = cb[2 * N_ + n] - mz;
        vm = fmaxf(vm, sqrtf(dx * dx + dy * dy + dz * dz));
    }
    for (int o = 32; o > 0; o >>= 1) vm = fmaxf(vm, __shfl_down(vm, o));
    if ((tid & 63) == 0) atomicMaxF(&stats[b * 8 + 3], vm);
}

// ---------------- feature transpose: fp32 [b][c][n] -> bf16 [b*N+n][c] ----------------
__global__ __launch_bounds__(256) void k_transpose(const float* __restrict__ feats,
                                                   unsigned short* __restrict__ featsT) {
    __shared__ float tile[64][65];
    int b = blockIdx.x >> 10;
    int n0 = (blockIdx.x & 1023) * 64;
    int t = threadIdx.x;
    {
        int c = t >> 2, x0 = (t & 3) * 16;
        const float* src = feats + ((size_t)b * 64 + c) * N_ + n0 + x0;
#pragma unroll
        for (int j = 0; j < 4; ++j) {
            float4 v = *(const float4*)(src + j * 4);
            tile[c][x0 + j * 4 + 0] = v.x;
            tile[c][x0 + j * 4 + 1] = v.y;
            tile[c][x0 + j * 4 + 2] = v.z;
            tile[c][x0 + j * 4 + 3] = v.w;
        }
    }
    __syncthreads();
    {
        int n = t >> 2, c0 = (t & 3) * 16;
        short8v s0, s1;
#pragma unroll
        for (int j = 0; j < 8; ++j) s0[j] = (short)f2bf(tile[c0 + j][n]);
#pragma unroll
        for (int j = 0; j < 8; ++j) s1[j] = (short)f2bf(tile[c0 + 8 + j][n]);
        unsigned short* dst = featsT + ((size_t)b * N_ + n0 + n) * 64 + c0;
        *(short8v*)(dst) = s0;
        *(short8v*)(dst + 8) = s1;
    }
}

// ---------------- voxel-id histogram + ncoords ----------------
__global__ __launch_bounds__(256) void k_hist(const float* __restrict__ coords,
                                              const float* __restrict__ stats,
                                              float* __restrict__ ncoords,
                                              unsigned* __restrict__ pvidx,
                                              unsigned* __restrict__ cnt) {
    int p = blockIdx.x * 256 + threadIdx.x;
    int b = p >> 16, n = p & (N_ - 1);
    const float* cb = coords + (size_t)b * 3 * N_;
    float mx = stats[b * 8 + 0] * (1.f / N_);
    float my = stats[b * 8 + 1] * (1.f / N_);
    float mz = stats[b * 8 + 2] * (1.f / N_);
    float s2 = stats[b * 8 + 3] * 2.0f;
    float cv[3] = {cb[n] - mx, cb[N_ + n] - my, cb[2 * N_ + n] - mz};
    int id[3];
#pragma unroll
    for (int d = 0; d < 3; ++d) {
        float t = cv[d] / s2 + 0.5f;
        float nc = fminf(fmaxf(t * (float)R_, 0.f), (float)(R_ - 1));
        ncoords[((size_t)b * 3 + d) * N_ + n] = nc;
        id[d] = (int)rintf(nc);   // round-half-even == jnp.round
    }
    unsigned v = (unsigned)(b * R3_ + id[0] * 1024 + id[1] * 32 + id[2]);
    pvidx[p] = v;
    atomicAdd(&cnt[v], 1u);
}

// ---------------- two-level exclusive scan over 262144 counts ----------------
__global__ __launch_bounds__(256) void k_scan1(const unsigned* __restrict__ cnt,
                                               unsigned* __restrict__ lp,
                                               unsigned* __restrict__ btot) {
    __shared__ unsigned sh[256];
    int t = threadIdx.x;
    int i0 = blockIdx.x * 1024 + t * 4;
    uint4 v = *(const uint4*)(cnt + i0);
    unsigned ts = v.x + v.y + v.z + v.w;
    sh[t] = ts;
    __syncthreads();
    for (int off = 1; off < 256; off <<= 1) {
        unsigned u = (t >= off) ? sh[t - off] : 0u;
        __syncthreads();
        sh[t] += u;
        __syncthreads();
    }
    unsigned ex = sh[t] - ts;
    uint4 o;
    o.x = ex;
    o.y = ex + v.x;
    o.z = ex + v.x + v.y;
    o.w = ex + v.x + v.y + v.z;
    *(uint4*)(lp + i0) = o;
    if (t == 255) btot[blockIdx.x] = sh[255];
}

__global__ __launch_bounds__(256) void k_scan2(unsigned* __restrict__ btot,
                                               unsigned* __restrict__ boff) {
    __shared__ unsigned sh[256];
    int t = threadIdx.x;
    unsigned ts = btot[t];
    sh[t] = ts;
    __syncthreads();
    for (int off = 1; off < 256; off <<= 1) {
        unsigned u = (t >= off) ? sh[t - off] : 0u;
        __syncthreads();
        sh[t] += u;
        __syncthreads();
    }
    boff[t] = sh[t] - ts;
}

// ---------------- rank: stable position within voxel -> order[] ----------------
__global__ __launch_bounds__(256) void k_rank(const unsigned* __restrict__ pvidx,
                                              const unsigned* __restrict__ lp,
                                              const unsigned* __restrict__ boff,
                                              unsigned* __restrict__ cnt,
                                              unsigned* __restrict__ order) {
    int p = blockIdx.x * 256 + threadIdx.x;
    unsigned v = pvidx[p];
    unsigned pos = atomicAdd(&cnt[v], 1u);
    order[lp[v] + boff[v >> 10] + pos] = (unsigned)p;
}

// ---------------- gather: wave per voxel, lane = channel; 4-way ILP; avg -> padded bf16 P0 ----------------
__global__ __launch_bounds__(256) void k_gather(const unsigned* __restrict__ order,
                                                const unsigned short* __restrict__ featsT,
                                                const unsigned* __restrict__ cnt,
                                                const unsigned* __restrict__ lp,
                                                const unsigned* __restrict__ boff,
                                                __hip_bfloat16* __restrict__ P0) {
    int gid = blockIdx.x * 256 + threadIdx.x;
    int v = gid >> 6;
    int lane = threadIdx.x & 63;
    unsigned base = lp[v] + boff[v >> 10];
    unsigned cv = cnt[v];
    float a0 = 0.f, a1 = 0.f, a2 = 0.f, a3 = 0.f;
    unsigned i = 0;
    for (; i + 4 <= cv; i += 4) {
        unsigned p0 = order[base + i];
        unsigned p1 = order[base + i + 1];
        unsigned p2 = order[base + i + 2];
        unsigned p3 = order[base + i + 3];
        a0 += bf2f((short)featsT[(size_t)p0 * 64 + lane]);
        a1 += bf2f((short)featsT[(size_t)p1 * 64 + lane]);
        a2 += bf2f((short)featsT[(size_t)p2 * 64 + lane]);
        a3 += bf2f((short)featsT[(size_t)p3 * 64 + lane]);
    }
    for (; i < cv; ++i) {
        unsigned p0 = order[base + i];
        a0 += bf2f((short)featsT[(size_t)p0 * 64 + lane]);
    }
    float acc = (a0 + a1) + (a2 + a3);
    float avg = (cv > 0) ? acc / (float)cv : 0.f;
    int b = v >> 15, loc = v & (R3_ - 1);
    int d0 = loc >> 10, d1 = (loc >> 5) & 31, d2 = loc & 31;
    P0[((size_t)b * RP3_ + (size_t)(d0 + 1) * RP2_ + (d1 + 1) * RP_ + (d2 + 1)) * 64 + lane] =
        __float2bfloat16(avg);
}

// ---------------- weight prep ----------------
__global__ __launch_bounds__(256) void k_wprep(const float* __restrict__ w1,
                                               const float* __restrict__ w2,
                                               __hip_bfloat16* __restrict__ wb,
                                               const float* __restrict__ mw,
                                               float* __restrict__ mwT) {
    int i = blockIdx.x * 256 + threadIdx.x;
    if (i < 2 * 27 * 64 * 64) {
        int conv = i / 110592;
        int r = i % 110592;
        int tap = r >> 12;
        int rr = r & 4095;
        int co = rr >> 6, ci = rr & 63;
        const float* src = conv ? w2 : w1;
        wb[i] = __float2bfloat16(src[(size_t)(co * 64 + ci) * 27 + tap]);
    }
    if (i < 4096) mwT[(i & 63) * 64 + (i >> 6)] = mw[i];
}

// ---------------- implicit-GEMM bf16 MFMA conv 3x3x3 + bias + BN + SiLU ----------------
// cout split across blockIdx.y (32 co per block). Tap loop fully unrolled (compile-time offsets).
__global__ __launch_bounds__(256, 2) void k_conv_mfma(const __hip_bfloat16* __restrict__ pin,
                                                      const __hip_bfloat16* __restrict__ wt,
                                                      const float* __restrict__ cbias,
                                                      const float* __restrict__ g,
                                                      const float* __restrict__ bb,
                                                      const float* __restrict__ bm,
                                                      const float* __restrict__ bv,
                                                      __hip_bfloat16* __restrict__ pout) {
    int wg = blockIdx.x;
    int ch = blockIdx.y;                 // 0/1: which 32-cout half
    int q = wg & 3, z = (wg >> 2) & 31, b = wg >> 7;
    int tid = threadIdx.x;
    int wave = tid >> 6, lane = tid & 63;
    int l15 = lane & 15, lk = lane >> 4;

    int yv[4], xv[4], Pb[4];
#pragma unroll
    for (int t = 0; t < 4; ++t) {
        yv[t] = q * 8 + wave * 2 + (t >> 1);
        xv[t] = (t & 1) * 16 + l15;
        Pb[t] = (yv[t] * RP_ + xv[t]) * 64 + lk * 8;
    }
    int Pa[2];
#pragma unroll
    for (int m = 0; m < 2; ++m) Pa[m] = (ch * 32 + m * 16 + l15) * 64 + lk * 8;

    const __hip_bfloat16* pb = pin + (size_t)b * RP3_ * 64 + (size_t)z * RP2_ * 64;
    floatx4 acc[2][4];
#pragma unroll
    for (int m = 0; m < 2; ++m)
#pragma unroll
        for (int t = 0; t < 4; ++t) acc[m][t] = (floatx4){0.f, 0.f, 0.f, 0.f};

#pragma unroll
    for (int dz = 0; dz < 3; ++dz) {
#pragma unroll
        for (int dy = 0; dy < 3; ++dy) {
#pragma unroll
            for (int dx = 0; dx < 3; ++dx) {
                const __hip_bfloat16* ptap = pb + (size_t)((dz * RP_ + dy) * RP_ + dx) * 64;
                const __hip_bfloat16* wtap = wt + ((dz * 3 + dy) * 3 + dx) * 4096;
#pragma unroll
                for (int ks = 0; ks < 2; ++ks) {
                    short8v a0 = *(const short8v*)(wtap + Pa[0] + ks * 32);
                    short8v a1 = *(const short8v*)(wtap + Pa[1] + ks * 32);
                    short8v b0 = *(const short8v*)(ptap + Pb[0] + ks * 32);
                    short8v b1 = *(const short8v*)(ptap + Pb[1] + ks * 32);
                    short8v b2 = *(const short8v*)(ptap + Pb[2] + ks * 32);
                    short8v b3 = *(const short8v*)(ptap + Pb[3] + ks * 32);
                    acc[0][0] = __builtin_amdgcn_mfma_f32_16x16x32_bf16(a0, b0, acc[0][0], 0, 0, 0);
                    acc[0][1] = __builtin_amdgcn_mfma_f32_16x16x32_bf16(a0, b1, acc[0][1], 0, 0, 0);
                    acc[0][2] = __builtin_amdgcn_mfma_f32_16x16x32_bf16(a0, b2, acc[0][2], 0, 0, 0);
                    acc[0][3] = __builtin_amdgcn_mfma_f32_16x16x32_bf16(a0, b3, acc[0][3], 0, 0, 0);
                    acc[1][0] = __builtin_amdgcn_mfma_f32_16x16x32_bf16(a1, b0, acc[1][0], 0, 0, 0);
                    acc[1][1] = __builtin_amdgcn_mfma_f32_16x16x32_bf16(a1, b1, acc[1][1], 0, 0, 0);
                    acc[1][2] = __builtin_amdgcn_mfma_f32_16x16x32_bf16(a1, b2, acc[1][2], 0, 0, 0);
                    acc[1][3] = __builtin_amdgcn_mfma_f32_16x16x32_bf16(a1, b3, acc[1][3], 0, 0, 0);
                }
            }
        }
    }

    __hip_bfloat16* ob = pout + (size_t)b * RP3_ * 64;
#pragma unroll
    for (int m = 0; m < 2; ++m) {
        int cb = ch * 32 + m * 16 + lk * 4;
        float4 g4 = *(const float4*)(g + cb);
        float4 b4 = *(const float4*)(bb + cb);
        float4 m4 = *(const float4*)(bm + cb);
        float4 v4 = *(const float4*)(bv + cb);
        float4 bi = *(const float4*)(cbias + cb);
        float s0 = g4.x * rsqrtf(v4.x + 1e-5f), s1 = g4.y * rsqrtf(v4.y + 1e-5f);
        float s2 = g4.z * rsqrtf(v4.z + 1e-5f), s3 = g4.w * rsqrtf(v4.w + 1e-5f);
        float t0 = b4.x - m4.x * s0, t1 = b4.y - m4.y * s1;
        float t2 = b4.z - m4.z * s2, t3 = b4.w - m4.w * s3;
#pragma unroll
        for (int t = 0; t < 4; ++t) {
            float r0 = (acc[m][t][0] + bi.x) * s0 + t0;
            float r1 = (acc[m][t][1] + bi.y) * s1 + t1;
            float r2 = (acc[m][t][2] + bi.z) * s2 + t2;
            float r3 = (acc[m][t][3] + bi.w) * s3 + t3;
            r0 = r0 / (1.0f + expf(-r0));
            r1 = r1 / (1.0f + expf(-r1));
            r2 = r2 / (1.0f + expf(-r2));
            r3 = r3 / (1.0f + expf(-r3));
            unsigned lo = (unsigned)f2bf(r0) | ((unsigned)f2bf(r1) << 16);
            unsigned hi = (unsigned)f2bf(r2) | ((unsigned)f2bf(r3) << 16);
            uint2 pk = {lo, hi};
            *(uint2*)(ob + (size_t)(((z + 1) * RP_ + yv[t] + 1) * RP_ + xv[t] + 1) * 64 + cb) = pk;
        }
    }
}

// ---------------- devoxelize + MLP + BN3 + ReLU + add (cout split 2-ways) ----------------
__global__ __launch_bounds__(256) void k_fuse(const __hip_bfloat16* __restrict__ P2,
                                              const float* __restrict__ ncoords,
                                              const float* __restrict__ feats,
                                              const float* __restrict__ mwT,
                                              const float* __restrict__ mb,
                                              const float* __restrict__ g,
                                              const float* __restrict__ bb,
                                              const float* __restrict__ bm,
                                              const float* __restrict__ bv,
                                              float* __restrict__ out) {
    int p = blockIdx.x * 256 + threadIdx.x;
    int b = p >> 16, n = p & (N_ - 1);
    int cbase = blockIdx.y * 32;

    float c0 = ncoords[((size_t)b * 3 + 0) * N_ + n];
    float c1 = ncoords[((size_t)b * 3 + 1) * N_ + n];
    float c2 = ncoords[((size_t)b * 3 + 2) * N_ + n];
    float fl0 = floorf(c0), fl1 = floorf(c1), fl2 = floorf(c2);
    float f0 = c0 - fl0, f1 = c1 - fl1, f2 = c2 - fl2;
    int a0 = (int)fl0, a1 = (int)fl1, a2 = (int)fl2;
    int h0 = min(a0 + 1, R_ - 1), h1 = min(a1 + 1, R_ - 1), h2 = min(a2 + 1, R_ - 1);

    int pvo[8];
    float wct[8];
    {
        int x0 = a0 + 1, x1 = h0 + 1, y0 = a1 + 1, y1 = h1 + 1, z0 = a2 + 1, z1 = h2 + 1;
        pvo[0] = (x0 * RP_ + y0) * RP_ + z0;  wct[0] = (1 - f0) * (1 - f1) * (1 - f2);
        pvo[1] = (x0 * RP_ + y0) * RP_ + z1;  wct[1] = (1 - f0) * (1 - f1) * f2;
        pvo[2] = (x0 * RP_ + y1) * RP_ + z0;  wct[2] = (1 - f0) * f1 * (1 - f2);
        pvo[3] = (x0 * RP_ + y1) * RP_ + z1;  wct[3] = (1 - f0) * f1 * f2;
        pvo[4] = (x1 * RP_ + y0) * RP_ + z0;  wct[4] = f0 * (1 - f1) * (1 - f2);
        pvo[5] = (x1 * RP_ + y0) * RP_ + z1;  wct[5] = f0 * (1 - f1) * f2;
        pvo[6] = (x1 * RP_ + y1) * RP_ + z0;  wct[6] = f0 * f1 * (1 - f2);
        pvo[7] = (x1 * RP_ + y1) * RP_ + z1;  wct[7] = f0 * f1 * f2;
    }

    float acc[32];
#pragma unroll
    for (int co = 0; co < 32; ++co) acc[co] = 0.f;

    const float* fb = feats + (size_t)b * C_ * N_ + n;
#pragma unroll 4
    for (int ci = 0; ci < 64; ++ci) {
        float f = fb[(size_t)ci * N_];
        const float* wr = mwT + ci * 64 + cbase;
#pragma unroll
        for (int co = 0; co < 32; ++co) acc[co] += f * wr[co];
    }
#pragma unroll
    for (int co = 0; co < 32; ++co) {
        int cg = cbase + co;
        float s = g[cg] * rsqrtf(bv[cg] + 1e-5f);
        float tt = bb[cg] - bm[cg] * s;
        float ptv = (acc[co] + mb[cg]) * s + tt;
        acc[co] = fmaxf(ptv, 0.f);
    }

    const __hip_bfloat16* vb = P2 + (size_t)b * RP3_ * 64 + cbase;
#pragma unroll
    for (int k = 0; k < 8; ++k) {
        const short8v* vp = (const short8v*)(vb + (size_t)pvo[k] * 64);
        float wk = wct[k];
#pragma unroll
        for (int cj = 0; cj < 4; ++cj) {
            short8v v8 = vp[cj];
#pragma unroll
            for (int j = 0; j < 8; ++j) acc[cj * 8 + j] += wk * bf2f(v8[j]);
        }
    }
#pragma unroll
    for (int co = 0; co < 32; ++co)
        out[((size_t)b * C_ + cbase + co) * N_ + n] = acc[co];
}

// ---------------- launch ----------------
extern "C" void kernel_launch(void* const* d_in, const int* in_sizes, int n_in,
                              void* d_out, int out_size, void* d_ws, size_t ws_size,
                              hipStream_t stream) {
    const float* features = (const float*)d_in[0];
    const float* coords   = (const float*)d_in[1];
    const float* time_emb = (const float*)d_in[2];
    const float* conv1_w  = (const float*)d_in[3];
    const float* conv1_b  = (const float*)d_in[4];
    const float* bn1_g = (const float*)d_in[5];
    const float* bn1_b = (const float*)d_in[6];
    const float* bn1_m = (const float*)d_in[7];
    const float* bn1_v = (const float*)d_in[8];
    const float* conv2_w  = (const float*)d_in[9];
    const float* conv2_b  = (const float*)d_in[10];
    const float* bn2_g = (const float*)d_in[11];
    const float* bn2_b = (const float*)d_in[12];
    const float* bn2_m = (const float*)d_in[13];
    const float* bn2_v = (const float*)d_in[14];
    const float* mlp_w = (const float*)d_in[15];
    const float* mlp_b = (const float*)d_in[16];
    const float* bn3_g = (const float*)d_in[17];
    const float* bn3_b = (const float*)d_in[18];
    const float* bn3_m = (const float*)d_in[19];
    const float* bn3_v = (const float*)d_in[20];
    float* out = (float*)d_out;
    float* ws = (float*)d_ws;

    // workspace layout (float offsets).
    // Region A (16,777,216 f = 67.1 MB): featsT until k_gather finishes; then memset
    // and reused as P1 (bf16 padded, 40.2 MB).
    const size_t OFF_A     = 0;              // 16,777,216 f
    const size_t OFF_P0    = 16777216;       // 10,061,824 f (P0, later reused as P2)
    const size_t OFF_NC    = 26839040;       // 1,572,864 f
    const size_t OFF_PV    = 28411904;       // 524,288 u32
    const size_t OFF_ORD   = 28936192;       // 524,288 u32
    const size_t OFF_CNT   = 29460480;       // 262,144 u32
    const size_t OFF_LP    = 29722624;       // 262,144 u32
    const size_t OFF_BT    = 29984768;       // 256 u32
    const size_t OFF_BOFF  = 29985024;       // 256 u32
    const size_t OFF_STATS = 29985280;       // 64 f
    const size_t OFF_WB    = 29985344;       // 110,592 f (bf16 x 221,184)
    const size_t OFF_MWT   = 30095936;       // 4,096 f   end: 30,100,032 f = 120.4 MB

    unsigned short* featsT = (unsigned short*)(ws + OFF_A);
    __hip_bfloat16* P1 = (__hip_bfloat16*)(ws + OFF_A);
    __hip_bfloat16* P0 = (__hip_bfloat16*)(ws + OFF_P0);
    __hip_bfloat16* P2 = (__hip_bfloat16*)(ws + OFF_P0);
    float* ncrd  = ws + OFF_NC;
    unsigned* pvidx = (unsigned*)(ws + OFF_PV);
    unsigned* order = (unsigned*)(ws + OFF_ORD);
    unsigned* cnt   = (unsigned*)(ws + OFF_CNT);
    unsigned* lp    = (unsigned*)(ws + OFF_LP);
    unsigned* btot  = (unsigned*)(ws + OFF_BT);
    unsigned* boff  = (unsigned*)(ws + OFF_BOFF);
    float* stats = ws + OFF_STATS;
    __hip_bfloat16* wb = (__hip_bfloat16*)(ws + OFF_WB);
    float* mwT = ws + OFF_MWT;

    hipMemsetAsync(cnt, 0, 262144 * sizeof(unsigned), stream);
    hipMemsetAsync(stats, 0, 64 * sizeof(float), stream);
    hipMemsetAsync(P0, 0, (size_t)B_ * RP3_ * 64 * sizeof(__hip_bfloat16), stream);

    k_wprep<<<dim3(864), 256, 0, stream>>>(conv1_w, conv2_w, wb, mlp_w, mwT);
    k_stats_sum<<<dim3(32, B_), 256, 0, stream>>>(coords, stats);
    k_stats_max<<<dim3(32, B_), 256, 0, stream>>>(coords, stats);
    k_transpose<<<dim3(B_ * 1024), 256, 0, stream>>>(features, featsT);
    k_hist<<<dim3(B_ * N_ / 256), 256, 0, stream>>>(coords, stats, ncrd, pvidx, cnt);
    k_scan1<<<dim3(256), 256, 0, stream>>>(cnt, lp, btot);
    hipMemsetAsync(cnt, 0, 262144 * sizeof(unsigned), stream);   // reuse as rank counters
    k_scan2<<<dim3(1), 256, 0, stream>>>(btot, boff);
    k_rank<<<dim3(B_ * N_ / 256), 256, 0, stream>>>(pvidx, lp, boff, cnt, order);
    k_gather<<<dim3(B_ * R3_ / 4), 256, 0, stream>>>(order, featsT, cnt, lp, boff, P0);

    // featsT dead; zero region A for P1 halo, then convs
    hipMemsetAsync(P1, 0, (size_t)B_ * RP3_ * 64 * sizeof(__hip_bfloat16), stream);
    k_conv_mfma<<<dim3(B_ * 32 * 4, 2), 256, 0, stream>>>(P0, wb, conv1_b, bn1_g, bn1_b, bn1_m,
                                                          bn1_v, P1);
    k_conv_mfma<<<dim3(B_ * 32 * 4, 2), 256, 0, stream>>>(P1, wb + 110592, conv2_b, bn2_g, bn2_b,
                                                          bn2_m, bn2_v, P2);
    k_fuse<<<dim3(B_ * N_ / 256, 2), 256, 0, stream>>>(P2, ncrd, features, mwT, mlp_b, bn3_g,
                                                       bn3_b, bn3_m, bn3_v, out);

    hipMemcpyAsync(out + 33554432, coords, (size_t)(B_ * 3 * N_) * sizeof(float),
                   hipMemcpyDeviceToDevice, stream);
    hipMemcpyAsync(out + 35127296, time_emb, (size_t)(B_ * 64) * sizeof(float),
                   hipMemcpyDeviceToDevice, stream);
}

// Round 7
// 1229.626 us; speedup vs baseline: 1.0078x; 1.0078x over previous
//
#include <hip/hip_runtime.h>
#include <hip/hip_bf16.h>
#include <math.h>

#define B_   8
#define C_   64
#define N_   65536
#define R_   32
#define R3_  32768
#define RP_  34
#define RP2_ 1156      // 34*34
#define RP3_ 39304     // 34^3

typedef short short8v __attribute__((ext_vector_type(8)));
typedef float floatx4 __attribute__((ext_vector_type(4)));

__device__ inline float bf2f(short u) {
    return __uint_as_float(((unsigned)(unsigned short)u) << 16);
}
__device__ inline unsigned short f2bf(float f) {
    __hip_bfloat16 h = __float2bfloat16(f);
    return *reinterpret_cast<unsigned short*>(&h);
}
__device__ inline void atomicMaxF(float* addr, float v) {
    atomicMax((unsigned int*)addr, __float_as_uint(v));
}

// ---------------- stats ----------------
__global__ __launch_bounds__(256) void k_stats_sum(const float* __restrict__ coords,
                                                   float* __restrict__ stats) {
    int b = blockIdx.y;
    int tid = threadIdx.x;
    const float* cb = coords + (size_t)b * 3 * N_;
    float sx = 0.f, sy = 0.f, sz = 0.f;
    int base = blockIdx.x * 2048;
    for (int k = 0; k < 8; ++k) {
        int n = base + k * 256 + tid;
        sx += cb[n];
        sy += cb[N_ + n];
        sz += cb[2 * N_ + n];
    }
    for (int o = 32; o > 0; o >>= 1) {
        sx += __shfl_down(sx, o);
        sy += __shfl_down(sy, o);
        sz += __shfl_down(sz, o);
    }
    if ((tid & 63) == 0) {
        atomicAdd(&stats[b * 8 + 0], sx);
        atomicAdd(&stats[b * 8 + 1], sy);
        atomicAdd(&stats[b * 8 + 2], sz);
    }
}

__global__ __launch_bounds__(256) void k_stats_max(const float* __restrict__ coords,
                                                   float* __restrict__ stats) {
    int b = blockIdx.y;
    int tid = threadIdx.x;
    const float* cb = coords + (size_t)b * 3 * N_;
    float mx = stats[b * 8 + 0] * (1.f / N_);
    float my = stats[b * 8 + 1] * (1.f / N_);
    float mz = stats[b * 8 + 2] * (1.f / N_);
    float vm = 0.f;
    int base = blockIdx.x * 2048;
    for (int k = 0; k < 8; ++k) {
        int n = base + k * 256 + tid;
        float dx = cb[n] - mx, dy = cb[N_ + n] - my, dz = cb[2 * N_ + n] - mz;
        vm = fmaxf(vm, sqrtf(dx * dx + dy * dy + dz * dz));
    }
    for (int o = 32; o > 0; o >>= 1) vm = fmaxf(vm, __shfl_down(vm, o));
    if ((tid & 63) == 0) atomicMaxF(&stats[b * 8 + 3], vm);
}

// ---------------- feature transpose: fp32 [b][c][n] -> bf16 [b*N+n][c] ----------------
__global__ __launch_bounds__(256) void k_transpose(const float* __restrict__ feats,
                                                   unsigned short* __restrict__ featsT) {
    __shared__ float tile[64][65];
    int b = blockIdx.x >> 10;
    int n0 = (blockIdx.x & 1023) * 64;
    int t = threadIdx.x;
    {
        int c = t >> 2, x0 = (t & 3) * 16;
        const float* src = feats + ((size_t)b * 64 + c) * N_ + n0 + x0;
#pragma unroll
        for (int j = 0; j < 4; ++j) {
            float4 v = *(const float4*)(src + j * 4);
            tile[c][x0 + j * 4 + 0] = v.x;
            tile[c][x0 + j * 4 + 1] = v.y;
            tile[c][x0 + j * 4 + 2] = v.z;
            tile[c][x0 + j * 4 + 3] = v.w;
        }
    }
    __syncthreads();
    {
        int n = t >> 2, c0 = (t & 3) * 16;
        short8v s0, s1;
#pragma unroll
        for (int j = 0; j < 8; ++j) s0[j] = (short)f2bf(tile[c0 + j][n]);
#pragma unroll
        for (int j = 0; j < 8; ++j) s1[j] = (short)f2bf(tile[c0 + 8 + j][n]);
        unsigned short* dst = featsT + ((size_t)b * N_ + n0 + n) * 64 + c0;
        *(short8v*)(dst) = s0;
        *(short8v*)(dst + 8) = s1;
    }
}

// ---------------- voxel-id histogram + ncoords ----------------
__global__ __launch_bounds__(256) void k_hist(const float* __restrict__ coords,
                                              const float* __restrict__ stats,
                                              float* __restrict__ ncoords,
                                              unsigned* __restrict__ pvidx,
                                              unsigned* __restrict__ cnt) {
    int p = blockIdx.x * 256 + threadIdx.x;
    int b = p >> 16, n = p & (N_ - 1);
    const float* cb = coords + (size_t)b * 3 * N_;
    float mx = stats[b * 8 + 0] * (1.f / N_);
    float my = stats[b * 8 + 1] * (1.f / N_);
    float mz = stats[b * 8 + 2] * (1.f / N_);
    float s2 = stats[b * 8 + 3] * 2.0f;
    float cv[3] = {cb[n] - mx, cb[N_ + n] - my, cb[2 * N_ + n] - mz};
    int id[3];
#pragma unroll
    for (int d = 0; d < 3; ++d) {
        float t = cv[d] / s2 + 0.5f;
        float nc = fminf(fmaxf(t * (float)R_, 0.f), (float)(R_ - 1));
        ncoords[((size_t)b * 3 + d) * N_ + n] = nc;
        id[d] = (int)rintf(nc);   // round-half-even == jnp.round
    }
    unsigned v = (unsigned)(b * R3_ + id[0] * 1024 + id[1] * 32 + id[2]);
    pvidx[p] = v;
    atomicAdd(&cnt[v], 1u);
}

// ---------------- two-level exclusive scan over 262144 counts ----------------
__global__ __launch_bounds__(256) void k_scan1(const unsigned* __restrict__ cnt,
                                               unsigned* __restrict__ lp,
                                               unsigned* __restrict__ btot) {
    __shared__ unsigned sh[256];
    int t = threadIdx.x;
    int i0 = blockIdx.x * 1024 + t * 4;
    uint4 v = *(const uint4*)(cnt + i0);
    unsigned ts = v.x + v.y + v.z + v.w;
    sh[t] = ts;
    __syncthreads();
    for (int off = 1; off < 256; off <<= 1) {
        unsigned u = (t >= off) ? sh[t - off] : 0u;
        __syncthreads();
        sh[t] += u;
        __syncthreads();
    }
    unsigned ex = sh[t] - ts;
    uint4 o;
    o.x = ex;
    o.y = ex + v.x;
    o.z = ex + v.x + v.y;
    o.w = ex + v.x + v.y + v.z;
    *(uint4*)(lp + i0) = o;
    if (t == 255) btot[blockIdx.x] = sh[255];
}

__global__ __launch_bounds__(256) void k_scan2(unsigned* __restrict__ btot,
                                               unsigned* __restrict__ boff) {
    __shared__ unsigned sh[256];
    int t = threadIdx.x;
    unsigned ts = btot[t];
    sh[t] = ts;
    __syncthreads();
    for (int off = 1; off < 256; off <<= 1) {
        unsigned u = (t >= off) ? sh[t - off] : 0u;
        __syncthreads();
        sh[t] += u;
        __syncthreads();
    }
    boff[t] = sh[t] - ts;
}

// ---------------- rank: stable position within voxel -> order[] ----------------
__global__ __launch_bounds__(256) void k_rank(const unsigned* __restrict__ pvidx,
                                              const unsigned* __restrict__ lp,
                                              const unsigned* __restrict__ boff,
                                              unsigned* __restrict__ cnt,
                                              unsigned* __restrict__ order) {
    int p = blockIdx.x * 256 + threadIdx.x;
    unsigned v = pvidx[p];
    unsigned pos = atomicAdd(&cnt[v], 1u);
    order[lp[v] + boff[v >> 10] + pos] = (unsigned)p;
}

// ---------------- gather: wave per voxel, lane = channel; 4-way ILP; batch = bid&7 (XCD-pinned) ----------------
__global__ __launch_bounds__(256) void k_gather(const unsigned* __restrict__ order,
                                                const unsigned short* __restrict__ featsT,
                                                const unsigned* __restrict__ cnt,
                                                const unsigned* __restrict__ lp,
                                                const unsigned* __restrict__ boff,
                                                __hip_bfloat16* __restrict__ P0) {
    int bid = blockIdx.x;
    int b = bid & 7;                                   // batch -> XCD pin
    int vloc = ((bid >> 3) << 2) + (threadIdx.x >> 6); // 4 voxels per block
    int v = b * R3_ + vloc;
    int lane = threadIdx.x & 63;
    unsigned base = lp[v] + boff[v >> 10];
    unsigned cv = cnt[v];
    float a0 = 0.f, a1 = 0.f, a2 = 0.f, a3 = 0.f;
    unsigned i = 0;
    for (; i + 4 <= cv; i += 4) {
        unsigned p0 = order[base + i];
        unsigned p1 = order[base + i + 1];
        unsigned p2 = order[base + i + 2];
        unsigned p3 = order[base + i + 3];
        a0 += bf2f((short)featsT[(size_t)p0 * 64 + lane]);
        a1 += bf2f((short)featsT[(size_t)p1 * 64 + lane]);
        a2 += bf2f((short)featsT[(size_t)p2 * 64 + lane]);
        a3 += bf2f((short)featsT[(size_t)p3 * 64 + lane]);
    }
    for (; i < cv; ++i) {
        unsigned p0 = order[base + i];
        a0 += bf2f((short)featsT[(size_t)p0 * 64 + lane]);
    }
    float acc = (a0 + a1) + (a2 + a3);
    float avg = (cv > 0) ? acc / (float)cv : 0.f;
    int d0 = vloc >> 10, d1 = (vloc >> 5) & 31, d2 = vloc & 31;
    P0[((size_t)b * RP3_ + (size_t)(d0 + 1) * RP2_ + (d1 + 1) * RP_ + (d2 + 1)) * 64 + lane] =
        __float2bfloat16(avg);
}

// ---------------- weight prep ----------------
__global__ __launch_bounds__(256) void k_wprep(const float* __restrict__ w1,
                                               const float* __restrict__ w2,
                                               __hip_bfloat16* __restrict__ wb,
                                               const float* __restrict__ mw,
                                               float* __restrict__ mwT) {
    int i = blockIdx.x * 256 + threadIdx.x;
    if (i < 2 * 27 * 64 * 64) {
        int conv = i / 110592;
        int r = i % 110592;
        int tap = r >> 12;
        int rr = r & 4095;
        int co = rr >> 6, ci = rr & 63;
        const float* src = conv ? w2 : w1;
        wb[i] = __float2bfloat16(src[(size_t)(co * 64 + ci) * 27 + tap]);
    }
    if (i < 4096) mwT[(i & 63) * 64 + (i >> 6)] = mw[i];
}

// ---------------- implicit-GEMM bf16 MFMA conv 3x3x3 + bias + BN + SiLU ----------------
// Linear grid 2048; decode: batch = bid&7 (XCD pin), then ch (cout half, innermost),
// q (y-quarter), z. Each batch's ~5MB input stays resident in its XCD's 4MB L2.
__global__ __launch_bounds__(256, 2) void k_conv_mfma(const __hip_bfloat16* __restrict__ pin,
                                                      const __hip_bfloat16* __restrict__ wt,
                                                      const float* __restrict__ cbias,
                                                      const float* __restrict__ g,
                                                      const float* __restrict__ bb,
                                                      const float* __restrict__ bm,
                                                      const float* __restrict__ bv,
                                                      __hip_bfloat16* __restrict__ pout) {
    int bid = blockIdx.x;
    int b = bid & 7;              // batch -> XCD pin
    int idx = bid >> 3;
    int ch = idx & 1;             // cout half (adjacent dispatches share input tile)
    int q = (idx >> 1) & 3;       // y quarter
    int z = idx >> 3;             // z plane
    int tid = threadIdx.x;
    int wave = tid >> 6, lane = tid & 63;
    int l15 = lane & 15, lk = lane >> 4;

    int yv[4], xv[4], Pb[4];
#pragma unroll
    for (int t = 0; t < 4; ++t) {
        yv[t] = q * 8 + wave * 2 + (t >> 1);
        xv[t] = (t & 1) * 16 + l15;
        Pb[t] = (yv[t] * RP_ + xv[t]) * 64 + lk * 8;
    }
    int Pa[2];
#pragma unroll
    for (int m = 0; m < 2; ++m) Pa[m] = (ch * 32 + m * 16 + l15) * 64 + lk * 8;

    const __hip_bfloat16* pb = pin + (size_t)b * RP3_ * 64 + (size_t)z * RP2_ * 64;
    floatx4 acc[2][4];
#pragma unroll
    for (int m = 0; m < 2; ++m)
#pragma unroll
        for (int t = 0; t < 4; ++t) acc[m][t] = (floatx4){0.f, 0.f, 0.f, 0.f};

#pragma unroll
    for (int dz = 0; dz < 3; ++dz) {
#pragma unroll
        for (int dy = 0; dy < 3; ++dy) {
#pragma unroll
            for (int dx = 0; dx < 3; ++dx) {
                const __hip_bfloat16* ptap = pb + (size_t)((dz * RP_ + dy) * RP_ + dx) * 64;
                const __hip_bfloat16* wtap = wt + ((dz * 3 + dy) * 3 + dx) * 4096;
#pragma unroll
                for (int ks = 0; ks < 2; ++ks) {
                    short8v a0 = *(const short8v*)(wtap + Pa[0] + ks * 32);
                    short8v a1 = *(const short8v*)(wtap + Pa[1] + ks * 32);
                    short8v b0 = *(const short8v*)(ptap + Pb[0] + ks * 32);
                    short8v b1 = *(const short8v*)(ptap + Pb[1] + ks * 32);
                    short8v b2 = *(const short8v*)(ptap + Pb[2] + ks * 32);
                    short8v b3 = *(const short8v*)(ptap + Pb[3] + ks * 32);
                    acc[0][0] = __builtin_amdgcn_mfma_f32_16x16x32_bf16(a0, b0, acc[0][0], 0, 0, 0);
                    acc[0][1] = __builtin_amdgcn_mfma_f32_16x16x32_bf16(a0, b1, acc[0][1], 0, 0, 0);
                    acc[0][2] = __builtin_amdgcn_mfma_f32_16x16x32_bf16(a0, b2, acc[0][2], 0, 0, 0);
                    acc[0][3] = __builtin_amdgcn_mfma_f32_16x16x32_bf16(a0, b3, acc[0][3], 0, 0, 0);
                    acc[1][0] = __builtin_amdgcn_mfma_f32_16x16x32_bf16(a1, b0, acc[1][0], 0, 0, 0);
                    acc[1][1] = __builtin_amdgcn_mfma_f32_16x16x32_bf16(a1, b1, acc[1][1], 0, 0, 0);
                    acc[1][2] = __builtin_amdgcn_mfma_f32_16x16x32_bf16(a1, b2, acc[1][2], 0, 0, 0);
                    acc[1][3] = __builtin_amdgcn_mfma_f32_16x16x32_bf16(a1, b3, acc[1][3], 0, 0, 0);
                }
            }
        }
    }

    __hip_bfloat16* ob = pout + (size_t)b * RP3_ * 64;
#pragma unroll
    for (int m = 0; m < 2; ++m) {
        int cb = ch * 32 + m * 16 + lk * 4;
        float4 g4 = *(const float4*)(g + cb);
        float4 b4 = *(const float4*)(bb + cb);
        float4 m4 = *(const float4*)(bm + cb);
        float4 v4 = *(const float4*)(bv + cb);
        float4 bi = *(const float4*)(cbias + cb);
        float s0 = g4.x * rsqrtf(v4.x + 1e-5f), s1 = g4.y * rsqrtf(v4.y + 1e-5f);
        float s2 = g4.z * rsqrtf(v4.z + 1e-5f), s3 = g4.w * rsqrtf(v4.w + 1e-5f);
        float t0 = b4.x - m4.x * s0, t1 = b4.y - m4.y * s1;
        float t2 = b4.z - m4.z * s2, t3 = b4.w - m4.w * s3;
#pragma unroll
        for (int t = 0; t < 4; ++t) {
            float r0 = (acc[m][t][0] + bi.x) * s0 + t0;
            float r1 = (acc[m][t][1] + bi.y) * s1 + t1;
            float r2 = (acc[m][t][2] + bi.z) * s2 + t2;
            float r3 = (acc[m][t][3] + bi.w) * s3 + t3;
            r0 = r0 / (1.0f + expf(-r0));
            r1 = r1 / (1.0f + expf(-r1));
            r2 = r2 / (1.0f + expf(-r2));
            r3 = r3 / (1.0f + expf(-r3));
            unsigned lo = (unsigned)f2bf(r0) | ((unsigned)f2bf(r1) << 16);
            unsigned hi = (unsigned)f2bf(r2) | ((unsigned)f2bf(r3) << 16);
            uint2 pk = {lo, hi};
            *(uint2*)(ob + (size_t)(((z + 1) * RP_ + yv[t] + 1) * RP_ + xv[t] + 1) * 64 + cb) = pk;
        }
    }
}

// ---------------- devoxelize + MLP + BN3 + ReLU + add (cout split 2-ways, batch XCD-pinned) ----------------
__global__ __launch_bounds__(256) void k_fuse(const __hip_bfloat16* __restrict__ P2,
                                              const float* __restrict__ ncoords,
                                              const float* __restrict__ feats,
                                              const float* __restrict__ mwT,
                                              const float* __restrict__ mb,
                                              const float* __restrict__ g,
                                              const float* __restrict__ bb,
                                              const float* __restrict__ bm,
                                              const float* __restrict__ bv,
                                              float* __restrict__ out) {
    int bid = blockIdx.x;
    int b = bid & 7;                          // batch -> XCD pin
    int n = ((bid >> 3) << 8) + threadIdx.x;  // point index within batch
    int cbase = blockIdx.y * 32;

    float c0 = ncoords[((size_t)b * 3 + 0) * N_ + n];
    float c1 = ncoords[((size_t)b * 3 + 1) * N_ + n];
    float c2 = ncoords[((size_t)b * 3 + 2) * N_ + n];
    float fl0 = floorf(c0), fl1 = floorf(c1), fl2 = floorf(c2);
    float f0 = c0 - fl0, f1 = c1 - fl1, f2 = c2 - fl2;
    int a0 = (int)fl0, a1 = (int)fl1, a2 = (int)fl2;
    int h0 = min(a0 + 1, R_ - 1), h1 = min(a1 + 1, R_ - 1), h2 = min(a2 + 1, R_ - 1);

    int pvo[8];
    float wct[8];
    {
        int x0 = a0 + 1, x1 = h0 + 1, y0 = a1 + 1, y1 = h1 + 1, z0 = a2 + 1, z1 = h2 + 1;
        pvo[0] = (x0 * RP_ + y0) * RP_ + z0;  wct[0] = (1 - f0) * (1 - f1) * (1 - f2);
        pvo[1] = (x0 * RP_ + y0) * RP_ + z1;  wct[1] = (1 - f0) * (1 - f1) * f2;
        pvo[2] = (x0 * RP_ + y1) * RP_ + z0;  wct[2] = (1 - f0) * f1 * (1 - f2);
        pvo[3] = (x0 * RP_ + y1) * RP_ + z1;  wct[3] = (1 - f0) * f1 * f2;
        pvo[4] = (x1 * RP_ + y0) * RP_ + z0;  wct[4] = f0 * (1 - f1) * (1 - f2);
        pvo[5] = (x1 * RP_ + y0) * RP_ + z1;  wct[5] = f0 * (1 - f1) * f2;
        pvo[6] = (x1 * RP_ + y1) * RP_ + z0;  wct[6] = f0 * f1 * (1 - f2);
        pvo[7] = (x1 * RP_ + y1) * RP_ + z1;  wct[7] = f0 * f1 * f2;
    }

    float acc[32];
#pragma unroll
    for (int co = 0; co < 32; ++co) acc[co] = 0.f;

    const float* fb = feats + (size_t)b * C_ * N_ + n;
#pragma unroll 4
    for (int ci = 0; ci < 64; ++ci) {
        float f = fb[(size_t)ci * N_];
        const float* wr = mwT + ci * 64 + cbase;
#pragma unroll
        for (int co = 0; co < 32; ++co) acc[co] += f * wr[co];
    }
#pragma unroll
    for (int co = 0; co < 32; ++co) {
        int cg = cbase + co;
        float s = g[cg] * rsqrtf(bv[cg] + 1e-5f);
        float tt = bb[cg] - bm[cg] * s;
        float ptv = (acc[co] + mb[cg]) * s + tt;
        acc[co] = fmaxf(ptv, 0.f);
    }

    const __hip_bfloat16* vb = P2 + (size_t)b * RP3_ * 64 + cbase;
#pragma unroll
    for (int k = 0; k < 8; ++k) {
        const short8v* vp = (const short8v*)(vb + (size_t)pvo[k] * 64);
        float wk = wct[k];
#pragma unroll
        for (int cj = 0; cj < 4; ++cj) {
            short8v v8 = vp[cj];
#pragma unroll
            for (int j = 0; j < 8; ++j) acc[cj * 8 + j] += wk * bf2f(v8[j]);
        }
    }
#pragma unroll
    for (int co = 0; co < 32; ++co)
        out[((size_t)b * C_ + cbase + co) * N_ + n] = acc[co];
}

// ---------------- launch ----------------
extern "C" void kernel_launch(void* const* d_in, const int* in_sizes, int n_in,
                              void* d_out, int out_size, void* d_ws, size_t ws_size,
                              hipStream_t stream) {
    const float* features = (const float*)d_in[0];
    const float* coords   = (const float*)d_in[1];
    const float* time_emb = (const float*)d_in[2];
    const float* conv1_w  = (const float*)d_in[3];
    const float* conv1_b  = (const float*)d_in[4];
    const float* bn1_g = (const float*)d_in[5];
    const float* bn1_b = (const float*)d_in[6];
    const float* bn1_m = (const float*)d_in[7];
    const float* bn1_v = (const float*)d_in[8];
    const float* conv2_w  = (const float*)d_in[9];
    const float* conv2_b  = (const float*)d_in[10];
    const float* bn2_g = (const float*)d_in[11];
    const float* bn2_b = (const float*)d_in[12];
    const float* bn2_m = (const float*)d_in[13];
    const float* bn2_v = (const float*)d_in[14];
    const float* mlp_w = (const float*)d_in[15];
    const float* mlp_b = (const float*)d_in[16];
    const float* bn3_g = (const float*)d_in[17];
    const float* bn3_b = (const float*)d_in[18];
    const float* bn3_m = (const float*)d_in[19];
    const float* bn3_v = (const float*)d_in[20];
    float* out = (float*)d_out;
    float* ws = (float*)d_ws;

    // workspace layout (float offsets).
    // Region A (16,777,216 f = 67.1 MB): featsT until k_gather finishes; then memset
    // and reused as P1 (bf16 padded, 40.2 MB).
    const size_t OFF_A     = 0;              // 16,777,216 f
    const size_t OFF_P0    = 16777216;       // 10,061,824 f (P0, later reused as P2)
    const size_t OFF_NC    = 26839040;       // 1,572,864 f
    const size_t OFF_PV    = 28411904;       // 524,288 u32
    const size_t OFF_ORD   = 28936192;       // 524,288 u32
    const size_t OFF_CNT   = 29460480;       // 262,144 u32
    const size_t OFF_LP    = 29722624;       // 262,144 u32
    const size_t OFF_BT    = 29984768;       // 256 u32
    const size_t OFF_BOFF  = 29985024;       // 256 u32
    const size_t OFF_STATS = 29985280;       // 64 f
    const size_t OFF_WB    = 29985344;       // 110,592 f (bf16 x 221,184)
    const size_t OFF_MWT   = 30095936;       // 4,096 f   end: 30,100,032 f = 120.4 MB

    unsigned short* featsT = (unsigned short*)(ws + OFF_A);
    __hip_bfloat16* P1 = (__hip_bfloat16*)(ws + OFF_A);
    __hip_bfloat16* P0 = (__hip_bfloat16*)(ws + OFF_P0);
    __hip_bfloat16* P2 = (__hip_bfloat16*)(ws + OFF_P0);
    float* ncrd  = ws + OFF_NC;
    unsigned* pvidx = (unsigned*)(ws + OFF_PV);
    unsigned* order = (unsigned*)(ws + OFF_ORD);
    unsigned* cnt   = (unsigned*)(ws + OFF_CNT);
    unsigned* lp    = (unsigned*)(ws + OFF_LP);
    unsigned* btot  = (unsigned*)(ws + OFF_BT);
    unsigned* boff  = (unsigned*)(ws + OFF_BOFF);
    float* stats = ws + OFF_STATS;
    __hip_bfloat16* wb = (__hip_bfloat16*)(ws + OFF_WB);
    float* mwT = ws + OFF_MWT;

    hipMemsetAsync(cnt, 0, 262144 * sizeof(unsigned), stream);
    hipMemsetAsync(stats, 0, 64 * sizeof(float), stream);
    hipMemsetAsync(P0, 0, (size_t)B_ * RP3_ * 64 * sizeof(__hip_bfloat16), stream);

    k_wprep<<<dim3(864), 256, 0, stream>>>(conv1_w, conv2_w, wb, mlp_w, mwT);
    k_stats_sum<<<dim3(32, B_), 256, 0, stream>>>(coords, stats);
    k_stats_max<<<dim3(32, B_), 256, 0, stream>>>(coords, stats);
    k_transpose<<<dim3(B_ * 1024), 256, 0, stream>>>(features, featsT);
    k_hist<<<dim3(B_ * N_ / 256), 256, 0, stream>>>(coords, stats, ncrd, pvidx, cnt);
    k_scan1<<<dim3(256), 256, 0, stream>>>(cnt, lp, btot);
    hipMemsetAsync(cnt, 0, 262144 * sizeof(unsigned), stream);   // reuse as rank counters
    k_scan2<<<dim3(1), 256, 0, stream>>>(btot, boff);
    k_rank<<<dim3(B_ * N_ / 256), 256, 0, stream>>>(pvidx, lp, boff, cnt, order);
    k_gather<<<dim3(B_ * R3_ / 4), 256, 0, stream>>>(order, featsT, cnt, lp, boff, P0);

    // featsT dead; zero region A for P1 halo, then convs
    hipMemsetAsync(P1, 0, (size_t)B_ * RP3_ * 64 * sizeof(__hip_bfloat16), stream);
    k_conv_mfma<<<dim3(2048), 256, 0, stream>>>(P0, wb, conv1_b, bn1_g, bn1_b, bn1_m,
                                                bn1_v, P1);
    k_conv_mfma<<<dim3(2048), 256, 0, stream>>>(P1, wb + 110592, conv2_b, bn2_g, bn2_b,
                                                bn2_m, bn2_v, P2);
    k_fuse<<<dim3(B_ * N_ / 256, 2), 256, 0, stream>>>(P2, ncrd, features, mwT, mlp_b, bn3_g,
                                                       bn3_b, bn3_m, bn3_v, out);

    hipMemcpyAsync(out + 33554432, coords, (size_t)(B_ * 3 * N_) * sizeof(float),
                   hipMemcpyDeviceToDevice, stream);
    hipMemcpyAsync(out + 35127296, time_emb, (size_t)(B_ * 64) * sizeof(float),
                   hipMemcpyDeviceToDevice, stream);
}